// Round 4
// baseline (4689.717 us; speedup 1.0000x reference)
//
#include <hip/hip_runtime.h>
#include <math.h>

#define B_   8
#define T_   12
#define BT   96      // B*T
#define N_   1000
#define FIN  64
#define H_   8
#define FOUT 16
#define HF   128     // H*FOUT
#define E_   8000
#define BTG  16      // bt per k_att block

typedef unsigned short u16;
typedef unsigned int   u32;

__device__ __forceinline__ float bf2f(u16 u) {
    return __uint_as_float(((u32)u) << 16);
}
__device__ __forceinline__ void unpack2(u32 q, float& lo, float& hi) {
    lo = __uint_as_float(q << 16);
    hi = __uint_as_float(q & 0xffff0000u);
}
__device__ __forceinline__ u16 f2bf(float f) {
    u32 x = __float_as_uint(f);
    u32 r = (x + 0x7fffu + ((x >> 16) & 1u)) >> 16;   // RNE
    return (u16)r;
}

// ---------------------------------------------------------------------------
// Workspace carve (float-element offsets). Total 4,653,504 floats ~ 18.6 MB
// (under the 29.5 MB proven available in round 3).
// ---------------------------------------------------------------------------
#define OFF_FLAGS   0        // 4 ints
#define OFF_AS      4        // 512
#define OFF_AT      516      // 512
#define OFF_GMAX    1028     // 4
#define OFF_PART    1032     // 3072
#define OFF_OFFS    4104     // 1004 ints
#define OFF_CSR     5108     // 8000 ints
#define OFF_SRCA    13108    // 8000 ints
#define OFF_TRGA    21108    // 8000 ints
#define OFF_WP32    29108    // 8192
#define OFF_WS32    37300    // 8192
#define OFF_SSRC    45504    // 768000
#define OFF_STRG    813504   // 768000
#define OFF_XT      1581504  // xT bf16 [N][BT][64]: 6.144M u16 = 3.072M floats

// ---------------------------------------------------------------------------
// K-1: runtime layout detection (unchanged from round 3 — it works).
// ---------------------------------------------------------------------------
__global__ __launch_bounds__(256) void k_detect(const u32* __restrict__ xw,
                                                const u32* __restrict__ ew,
                                                int* __restrict__ flags)
{
    __shared__ int votes;
    __shared__ u32 orAcc;
    const int tid = threadIdx.x;
    if (tid == 0) { votes = 0; orAcc = 0u; }
    __syncthreads();

    const u32 w = xw[tid];
    const int e = (int)((w >> 7) & 0xFFu);
    if (e == 0 || (e >= 95 && e <= 140)) atomicAdd(&votes, 1);

    u32 o = 0;
    for (int i = 2 * tid + 1; i < 16000; i += 512) o |= ew[i];
    atomicOr(&orAcc, o);
    __syncthreads();

    if (tid == 0) {
        flags[0] = (votes >= 160) ? 1 : 0;
        flags[1] = (orAcc == 0u) ? 1 : 0;
    }
}

// ---------------------------------------------------------------------------
// K0a: x [bt][n][64] -> xT bf16 [n][bt][64]  (transpose + canonicalize)
// grid (N_, 3) x 256 thr; thread = (bt_local = tid>>3, k8 = tid&7), 8 u16.
// ---------------------------------------------------------------------------
__global__ __launch_bounds__(256) void k_convX(const void* __restrict__ xin,
                                               const int* __restrict__ flags,
                                               u16* __restrict__ xT)
{
    const int n  = blockIdx.x;
    const int bt = blockIdx.y * 32 + (threadIdx.x >> 3);
    const int k8 = threadIdx.x & 7;
    const size_t src = ((size_t)bt * N_ + n) * FIN + k8 * 8;
    const size_t dst = ((size_t)n * BT + bt) * FIN + k8 * 8;

    if (flags[0]) {   // bf16 passthrough
        *(uint4*)(xT + dst) = *(const uint4*)((const u16*)xin + src);
    } else {          // fp32 -> bf16
        const float4 f0 = *(const float4*)((const float*)xin + src);
        const float4 f1 = *(const float4*)((const float*)xin + src + 4);
        uint4 p;
        p.x = (u32)f2bf(f0.x) | ((u32)f2bf(f0.y) << 16);
        p.y = (u32)f2bf(f0.z) | ((u32)f2bf(f0.w) << 16);
        p.z = (u32)f2bf(f1.x) | ((u32)f2bf(f1.y) << 16);
        p.w = (u32)f2bf(f1.z) | ((u32)f2bf(f1.w) << 16);
        *(uint4*)(xT + dst) = p;
    }
}

// ---------------------------------------------------------------------------
// K0b: canonicalize W -> fp32 and fold attention vectors through W_proj.
// ---------------------------------------------------------------------------
__global__ __launch_bounds__(256) void k_prep(const void* __restrict__ Wp,
                                              const void* __restrict__ Ws,
                                              const void* __restrict__ as_,
                                              const void* __restrict__ at_,
                                              const int* __restrict__ flags,
                                              float* __restrict__ Wp32,
                                              float* __restrict__ Ws32,
                                              float* __restrict__ aS,
                                              float* __restrict__ aT)
{
    const int tid = threadIdx.x;
    const bool bf = flags[0] != 0;

    for (int i = tid; i < HF * FIN; i += 256) {
        Wp32[i] = bf ? bf2f(((const u16*)Wp)[i]) : ((const float*)Wp)[i];
        Ws32[i] = bf ? bf2f(((const u16*)Ws)[i]) : ((const float*)Ws)[i];
    }
    __syncthreads();

    for (int q = tid; q < H_ * FIN; q += 256) {
        const int h = q >> 6, k = q & 63;
        float s1 = 0.f, s2 = 0.f;
#pragma unroll
        for (int f = 0; f < FOUT; f++) {
            const float w = Wp32[(h * FOUT + f) * FIN + k];
            const float a1 = bf ? bf2f(((const u16*)as_)[h * FOUT + f])
                                : ((const float*)as_)[h * FOUT + f];
            const float a2 = bf ? bf2f(((const u16*)at_)[h * FOUT + f])
                                : ((const float*)at_)[h * FOUT + f];
            s1 = fmaf(a1, w, s1);
            s2 = fmaf(a2, w, s2);
        }
        aS[q] = s1;
        aT[q] = s2;
    }
}

// ---------------------------------------------------------------------------
// K0c: normalize edge_index -> int32 srcA/trgA (int64 or int32 input).
// ---------------------------------------------------------------------------
__global__ __launch_bounds__(256) void k_edges(const u32* __restrict__ ew,
                                               const int* __restrict__ flags,
                                               int* __restrict__ srcA,
                                               int* __restrict__ trgA)
{
    const int e = blockIdx.x * 256 + threadIdx.x;
    if (e >= E_) return;
    int s, t;
    if (flags[1]) { s = (int)ew[2 * e]; t = (int)ew[2 * (E_ + e)]; }
    else          { s = (int)ew[e];     t = (int)ew[E_ + e]; }
    srcA[e] = s;
    trgA[e] = t;
}

// ---------------------------------------------------------------------------
// K1: build CSR (edges grouped by target). Single block, 1024 threads.
// ---------------------------------------------------------------------------
__global__ __launch_bounds__(1024) void k_csr(const int* __restrict__ srcA,
                                              const int* __restrict__ trgA,
                                              int* __restrict__ offs,
                                              int* __restrict__ csr)
{
    __shared__ int cnt[1024];
    __shared__ int scan[1024];
    __shared__ int cursor[1024];
    const int tid = threadIdx.x;

    cnt[tid] = 0;
    __syncthreads();
    for (int e = tid; e < E_; e += 1024)
        atomicAdd(&cnt[trgA[e]], 1);
    __syncthreads();

    scan[tid] = cnt[tid];
    __syncthreads();
    for (int d = 1; d < 1024; d <<= 1) {
        int t = (tid >= d) ? scan[tid - d] : 0;
        __syncthreads();
        scan[tid] += t;
        __syncthreads();
    }
    int excl = (tid == 0) ? 0 : scan[tid - 1];
    cursor[tid] = excl;
    if (tid < N_) offs[tid] = excl;
    if (tid == 0) offs[N_] = E_;
    __syncthreads();

    for (int e = tid; e < E_; e += 1024) {
        int t = trgA[e];
        int pos = atomicAdd(&cursor[t], 1);
        csr[pos] = srcA[e];
    }
}

// ---------------------------------------------------------------------------
// K2: per-node scores from xT.  s_src[bt*N+n][h] = aS[h]·x, s_trg = aT[h]·x
// ---------------------------------------------------------------------------
__global__ __launch_bounds__(256) void k_scores(const u16* __restrict__ xT,
                                                const float* __restrict__ aS,
                                                const float* __restrict__ aT,
                                                float* __restrict__ s_src,
                                                float* __restrict__ s_trg)
{
    const int tid = threadIdx.x;
    const int n = blockIdx.x * 16 + (tid >> 4);
    if (n >= N_) return;
    const int d = tid & 15;
    const int h = d & 7;
    const int bt = blockIdx.y;

    const float4* ar = reinterpret_cast<const float4*>((d < 8 ? aS : aT) + h * FIN);
    const uint4*  xr = reinterpret_cast<const uint4*>(xT + ((size_t)n * BT + bt) * FIN);

    float acc = 0.f;
#pragma unroll
    for (int i = 0; i < 8; i++) {
        const uint4 q = xr[i];
        const float4 a0 = ar[2 * i], a1 = ar[2 * i + 1];
        float lo, hi;
        unpack2(q.x, lo, hi); acc = fmaf(lo, a0.x, acc); acc = fmaf(hi, a0.y, acc);
        unpack2(q.y, lo, hi); acc = fmaf(lo, a0.z, acc); acc = fmaf(hi, a0.w, acc);
        unpack2(q.z, lo, hi); acc = fmaf(lo, a1.x, acc); acc = fmaf(hi, a1.y, acc);
        unpack2(q.w, lo, hi); acc = fmaf(lo, a1.z, acc); acc = fmaf(hi, a1.w, acc);
    }
    (d < 8 ? s_src : s_trg)[((size_t)bt * N_ + n) * H_ + h] = acc;
}

// ---------------------------------------------------------------------------
// K3/K3b: global max of leaky_relu scores
// ---------------------------------------------------------------------------
__global__ __launch_bounds__(256) void k_max(const int* __restrict__ srcA,
                                             const int* __restrict__ trgA,
                                             const float* __restrict__ s_src,
                                             const float* __restrict__ s_trg,
                                             float* __restrict__ partial)
{
    const int e  = blockIdx.x * 256 + threadIdx.x;
    const int bt = blockIdx.y;
    float m = -INFINITY;
    if (e < E_) {
        const int s = srcA[e], g = trgA[e];
        const float* ps = s_src + ((size_t)bt * N_ + s) * H_;
        const float* pt = s_trg + ((size_t)bt * N_ + g) * H_;
#pragma unroll
        for (int h = 0; h < H_; h++) {
            float sc = ps[h] + pt[h];
            sc = fmaxf(sc, 0.2f * sc);
            m = fmaxf(m, sc);
        }
    }
#pragma unroll
    for (int d = 32; d >= 1; d >>= 1) m = fmaxf(m, __shfl_xor(m, d, 64));
    __shared__ float wm[4];
    const int tid = threadIdx.x;
    if ((tid & 63) == 0) wm[tid >> 6] = m;
    __syncthreads();
    if (tid == 0)
        partial[bt * gridDim.x + blockIdx.x] =
            fmaxf(fmaxf(wm[0], wm[1]), fmaxf(wm[2], wm[3]));
}

__global__ __launch_bounds__(1024) void k_max2(const float* __restrict__ partial,
                                               float* __restrict__ gmax, int np)
{
    const int tid = threadIdx.x;
    float m = -INFINITY;
    for (int i = tid; i < np; i += 1024) m = fmaxf(m, partial[i]);
#pragma unroll
    for (int d = 32; d >= 1; d >>= 1) m = fmaxf(m, __shfl_xor(m, d, 64));
    __shared__ float wm[16];
    if ((tid & 63) == 0) wm[tid >> 6] = m;
    __syncthreads();
    if (tid == 0) {
        float r = -INFINITY;
#pragma unroll
        for (int i = 0; i < 16; i++) r = fmaxf(r, wm[i]);
        *gmax = r;
    }
}

// ---------------------------------------------------------------------------
// K4: fused GAT block. grid (N_, 6), 128 thr = 16 bt x 8 h.
// Thread (bt,h): y[64] register accumulator in x-space over CSR neighbors,
// 1 exp/edge; normalize by den; then 16 f-outputs = Wp[h*16+f]·y + Ws·xt,
// ELU, store. No cross-lane ops; W rows stream from L1.
// ---------------------------------------------------------------------------
__global__ __launch_bounds__(128) void k_att(const u16* __restrict__ xT,
                                             const float* __restrict__ Wp32,
                                             const float* __restrict__ Ws32,
                                             const float* __restrict__ s_src,
                                             const float* __restrict__ s_trg,
                                             const int* __restrict__ offs,
                                             const int* __restrict__ csr,
                                             const float* __restrict__ gmaxp,
                                             const int* __restrict__ flags,
                                             void* __restrict__ out)
{
    const int n   = blockIdx.x;
    const int tid = threadIdx.x;
    const int bt  = blockIdx.y * BTG + (tid >> 3);
    const int h   = tid & 7;

    __shared__ int csrL[64];

    const float g  = *gmaxp;
    const float st = s_trg[((size_t)bt * N_ + n) * H_ + h];

    float y[FIN];
#pragma unroll
    for (int k = 0; k < FIN; k++) y[k] = 0.f;
    float den = 0.f;

    const int e0 = offs[n], e1 = offs[n + 1];
    for (int base = e0; base < e1; base += 64) {
        const int cnt = min(64, e1 - base);
        __syncthreads();
        if (tid < cnt) csrL[tid] = csr[base + tid];
        __syncthreads();

        for (int i = 0; i < cnt; i++) {
            const int s = csrL[i];
            const float ss = s_src[((size_t)bt * N_ + s) * H_ + h];
            float sc = ss + st;
            sc = fmaxf(sc, 0.2f * sc);                 // leaky_relu(0.2)
            const float w = __expf(sc - g);
            den += w;

            const uint4* xr = reinterpret_cast<const uint4*>(
                xT + ((size_t)s * BT + bt) * FIN);
#pragma unroll
            for (int c = 0; c < 8; c++) {
                const uint4 q = xr[c];
                const int kb = c * 8;
                float lo, hi;
                unpack2(q.x, lo, hi);
                y[kb+0] = fmaf(w, lo, y[kb+0]); y[kb+1] = fmaf(w, hi, y[kb+1]);
                unpack2(q.y, lo, hi);
                y[kb+2] = fmaf(w, lo, y[kb+2]); y[kb+3] = fmaf(w, hi, y[kb+3]);
                unpack2(q.z, lo, hi);
                y[kb+4] = fmaf(w, lo, y[kb+4]); y[kb+5] = fmaf(w, hi, y[kb+5]);
                unpack2(q.w, lo, hi);
                y[kb+6] = fmaf(w, lo, y[kb+6]); y[kb+7] = fmaf(w, hi, y[kb+7]);
            }
        }
    }

    // normalize: att = y / (den + 1e-16)
    const float rden = 1.0f / (den + 1e-16f);
#pragma unroll
    for (int k = 0; k < FIN; k++) y[k] *= rden;

    // target row (for skip), kept packed: 8 uint4 = 32 regs
    uint4 xq[8];
    {
        const uint4* xtr = reinterpret_cast<const uint4*>(
            xT + ((size_t)n * BT + bt) * FIN);
#pragma unroll
        for (int c = 0; c < 8; c++) xq[c] = xtr[c];
    }

    float acc[FOUT];
#pragma unroll
    for (int f = 0; f < FOUT; f++) acc[f] = 0.f;

    const float* wpB = Wp32 + (size_t)(h * FOUT) * FIN;
    const float* wsB = Ws32 + (size_t)(h * FOUT) * FIN;

#pragma unroll
    for (int c = 0; c < 8; c++) {          // 8 chunks of 8 k
        float xv[8];
        {
            float lo, hi;
            unpack2(xq[c].x, lo, hi); xv[0] = lo; xv[1] = hi;
            unpack2(xq[c].y, lo, hi); xv[2] = lo; xv[3] = hi;
            unpack2(xq[c].z, lo, hi); xv[4] = lo; xv[5] = hi;
            unpack2(xq[c].w, lo, hi); xv[6] = lo; xv[7] = hi;
        }
        const int kb = c * 8;
#pragma unroll
        for (int f = 0; f < FOUT; f++) {
            const float4 wp0 = *(const float4*)(wpB + f * FIN + kb);
            const float4 wp1 = *(const float4*)(wpB + f * FIN + kb + 4);
            const float4 ws0 = *(const float4*)(wsB + f * FIN + kb);
            const float4 ws1 = *(const float4*)(wsB + f * FIN + kb + 4);
            float a = acc[f];
            a = fmaf(wp0.x, y[kb+0], a); a = fmaf(wp0.y, y[kb+1], a);
            a = fmaf(wp0.z, y[kb+2], a); a = fmaf(wp0.w, y[kb+3], a);
            a = fmaf(wp1.x, y[kb+4], a); a = fmaf(wp1.y, y[kb+5], a);
            a = fmaf(wp1.z, y[kb+6], a); a = fmaf(wp1.w, y[kb+7], a);
            a = fmaf(ws0.x, xv[0], a);  a = fmaf(ws0.y, xv[1], a);
            a = fmaf(ws0.z, xv[2], a);  a = fmaf(ws0.w, xv[3], a);
            a = fmaf(ws1.x, xv[4], a);  a = fmaf(ws1.y, xv[5], a);
            a = fmaf(ws1.z, xv[6], a);  a = fmaf(ws1.w, xv[7], a);
            acc[f] = a;
        }
    }

    // ELU + store 16 outputs (32 B contiguous per thread)
#pragma unroll
    for (int f = 0; f < FOUT; f++)
        acc[f] = acc[f] > 0.f ? acc[f] : expm1f(acc[f]);

    const size_t obase = ((size_t)bt * N_ + n) * HF + h * FOUT;
    if (flags[0]) {
        uint4 p0, p1;
        p0.x = (u32)f2bf(acc[0])  | ((u32)f2bf(acc[1])  << 16);
        p0.y = (u32)f2bf(acc[2])  | ((u32)f2bf(acc[3])  << 16);
        p0.z = (u32)f2bf(acc[4])  | ((u32)f2bf(acc[5])  << 16);
        p0.w = (u32)f2bf(acc[6])  | ((u32)f2bf(acc[7])  << 16);
        p1.x = (u32)f2bf(acc[8])  | ((u32)f2bf(acc[9])  << 16);
        p1.y = (u32)f2bf(acc[10]) | ((u32)f2bf(acc[11]) << 16);
        p1.z = (u32)f2bf(acc[12]) | ((u32)f2bf(acc[13]) << 16);
        p1.w = (u32)f2bf(acc[14]) | ((u32)f2bf(acc[15]) << 16);
        uint4* op = (uint4*)((u16*)out + obase);
        op[0] = p0;
        op[1] = p1;
    } else {
        float* op = (float*)out + obase;
#pragma unroll
        for (int c = 0; c < 4; c++)
            *(float4*)(op + c * 4) = make_float4(acc[c*4], acc[c*4+1],
                                                 acc[c*4+2], acc[c*4+3]);
    }
}

// ---------------------------------------------------------------------------
extern "C" void kernel_launch(void* const* d_in, const int* in_sizes, int n_in,
                              void* d_out, int out_size, void* d_ws, size_t ws_size,
                              hipStream_t stream)
{
    const void* x   = d_in[0];
    const u32*  ew  = (const u32*)d_in[1];
    const void* Wp  = d_in[2];
    const void* as_ = d_in[3];
    const void* at_ = d_in[4];
    const void* Ws  = d_in[5];

    float* ws      = (float*)d_ws;
    int*   flags   = (int*)(ws + OFF_FLAGS);
    float* aS      = ws + OFF_AS;
    float* aT      = ws + OFF_AT;
    float* gmax    = ws + OFF_GMAX;
    float* partial = ws + OFF_PART;
    int*   offs    = (int*)(ws + OFF_OFFS);
    int*   csr     = (int*)(ws + OFF_CSR);
    int*   srcA    = (int*)(ws + OFF_SRCA);
    int*   trgA    = (int*)(ws + OFF_TRGA);
    float* Wp32    = ws + OFF_WP32;
    float* Ws32    = ws + OFF_WS32;
    float* s_src   = ws + OFF_SSRC;
    float* s_trg   = ws + OFF_STRG;
    u16*   xT      = (u16*)(ws + OFF_XT);

    k_detect<<<1, 256, 0, stream>>>((const u32*)x, ew, flags);
    k_convX <<<dim3(N_, 3), 256, 0, stream>>>(x, flags, xT);
    k_prep  <<<1, 256, 0, stream>>>(Wp, Ws, as_, at_, flags, Wp32, Ws32, aS, aT);
    k_edges <<<32, 256, 0, stream>>>(ew, flags, srcA, trgA);
    k_csr   <<<1, 1024, 0, stream>>>(srcA, trgA, offs, csr);
    k_scores<<<dim3((N_ + 15) / 16, BT), 256, 0, stream>>>(xT, aS, aT, s_src, s_trg);
    k_max   <<<dim3(32, BT), 256, 0, stream>>>(srcA, trgA, s_src, s_trg, partial);
    k_max2  <<<1, 1024, 0, stream>>>(partial, gmax, 32 * BT);
    k_att   <<<dim3(N_, BT / BTG), 128, 0, stream>>>(xT, Wp32, Ws32, s_src, s_trg,
                                                     offs, csr, gmax, flags, d_out);
}

// Round 5
// 360.083 us; speedup vs baseline: 13.0240x; 13.0240x over previous
//
#include <hip/hip_runtime.h>
#include <math.h>

#define B_   8
#define T_   12
#define BT   96      // B*T
#define N_   1000
#define FIN  64
#define H_   8
#define FOUT 16
#define HF   128     // H*FOUT
#define E_   8000

typedef unsigned short u16;
typedef unsigned int   u32;

__device__ __forceinline__ float bf2f(u16 u) {
    return __uint_as_float(((u32)u) << 16);
}
__device__ __forceinline__ void unpack2(u32 q, float& lo, float& hi) {
    lo = __uint_as_float(q << 16);
    hi = __uint_as_float(q & 0xffff0000u);
}
__device__ __forceinline__ u16 f2bf(float f) {
    u32 x = __float_as_uint(f);
    u32 r = (x + 0x7fffu + ((x >> 16) & 1u)) >> 16;   // RNE
    return (u16)r;
}

// ---------------------------------------------------------------------------
// Workspace carve (float-element offsets). Total 13,850,676 floats ~ 55.4 MB.
// ---------------------------------------------------------------------------
#define OFF_FLAGS   0         // 4 ints
#define OFF_AS      4         // 512
#define OFF_AT      516       // 512
#define OFF_GMAX    1028      // 4
#define OFF_PART    1032      // 256 (pss @ +0, pst @ +128)
#define OFF_OFFS    1288      // 1004 ints
#define OFF_CSR     2292      // 8000 ints (src per edge, grouped by target)
#define OFF_WP32    10292     // 8192
#define OFF_WS32    18484     // 8192
#define OFF_STS     26676     // 768000  sT_src fp32 [n][bt][8]
#define OFF_STT     794676    // 768000  sT_trg fp32 [n][bt][8]
#define OFF_PROJ    1562676   // projT bf16 [n][bt][128] = 12.288M u16
#define OFF_SKIP    7706676   // skipT bf16 [n][bt][128]
// end: 13,850,676

// ---------------------------------------------------------------------------
// K0: detect layouts + canonicalize W to fp32 + fold a through W_proj.
//  flags[0]=1 iff float tensors are bf16; flags[1]=1 iff edge_index is int64.
// ---------------------------------------------------------------------------
__global__ __launch_bounds__(256) void k_prep(const u32* __restrict__ xw,
                                              const u32* __restrict__ ew,
                                              const void* __restrict__ Wp,
                                              const void* __restrict__ Ws,
                                              const void* __restrict__ as_,
                                              const void* __restrict__ at_,
                                              int* __restrict__ flags,
                                              float* __restrict__ Wp32,
                                              float* __restrict__ Ws32,
                                              float* __restrict__ aS,
                                              float* __restrict__ aT)
{
    __shared__ float WpL[HF * FIN];   // 32 KB
    __shared__ int votes;
    __shared__ u32 orAcc;
    __shared__ int flagL;
    const int tid = threadIdx.x;

    if (tid == 0) { votes = 0; orAcc = 0u; }
    __syncthreads();

    // bf16-vs-fp32 probe on x
    {
        const u32 w = xw[tid];
        const int e = (int)((w >> 7) & 0xFFu);
        if (e == 0 || (e >= 95 && e <= 140)) atomicAdd(&votes, 1);
    }
    // int64-vs-int32 probe on edge_index
    {
        u32 o = 0;
        for (int i = 2 * tid + 1; i < 16000; i += 512) o |= ew[i];
        atomicOr(&orAcc, o);
    }
    __syncthreads();
    if (tid == 0) {
        flagL = (votes >= 160) ? 1 : 0;
        flags[0] = flagL;
        flags[1] = (orAcc == 0u) ? 1 : 0;
    }
    __syncthreads();
    const bool bf = flagL != 0;

    for (int i = tid; i < HF * FIN; i += 256) {
        const float wp = bf ? bf2f(((const u16*)Wp)[i]) : ((const float*)Wp)[i];
        const float wsv = bf ? bf2f(((const u16*)Ws)[i]) : ((const float*)Ws)[i];
        WpL[i] = wp;
        Wp32[i] = wp;
        Ws32[i] = wsv;
    }
    __syncthreads();

    for (int q = tid; q < H_ * FIN; q += 256) {
        const int h = q >> 6, k = q & 63;
        float s1 = 0.f, s2 = 0.f;
#pragma unroll
        for (int f = 0; f < FOUT; f++) {
            const float w = WpL[(h * FOUT + f) * FIN + k];
            const float a1 = bf ? bf2f(((const u16*)as_)[h * FOUT + f])
                                : ((const float*)as_)[h * FOUT + f];
            const float a2 = bf ? bf2f(((const u16*)at_)[h * FOUT + f])
                                : ((const float*)at_)[h * FOUT + f];
            s1 = fmaf(a1, w, s1);
            s2 = fmaf(a2, w, s2);
        }
        aS[q] = s1;
        aT[q] = s2;
    }
}

// ---------------------------------------------------------------------------
// K1: decode edges + build CSR (edges grouped by target). 1 block, 1024 thr.
// ---------------------------------------------------------------------------
__global__ __launch_bounds__(1024) void k_csr(const u32* __restrict__ ew,
                                              const int* __restrict__ flags,
                                              int* __restrict__ offs,
                                              int* __restrict__ csrS)
{
    __shared__ int cnt[1024];
    __shared__ int scan[1024];
    __shared__ int cursor[1024];
    const int tid = threadIdx.x;
    const bool i64 = flags[1] != 0;

    cnt[tid] = 0;
    __syncthreads();
    for (int e = tid; e < E_; e += 1024) {
        const int t = i64 ? (int)ew[2 * (E_ + e)] : (int)ew[E_ + e];
        atomicAdd(&cnt[t], 1);
    }
    __syncthreads();

    scan[tid] = cnt[tid];
    __syncthreads();
    for (int d = 1; d < 1024; d <<= 1) {
        int t = (tid >= d) ? scan[tid - d] : 0;
        __syncthreads();
        scan[tid] += t;
        __syncthreads();
    }
    int excl = (tid == 0) ? 0 : scan[tid - 1];
    cursor[tid] = excl;
    if (tid < N_) offs[tid] = excl;
    if (tid == 0) offs[N_] = E_;
    __syncthreads();

    for (int e = tid; e < E_; e += 1024) {
        const int s = i64 ? (int)ew[2 * e] : (int)ew[e];
        const int t = i64 ? (int)ew[2 * (E_ + e)] : (int)ew[E_ + e];
        int pos = atomicAdd(&cursor[t], 1);
        csrS[pos] = s;
    }
}

// ---------------------------------------------------------------------------
// K2: proj + skip matvecs (bf16 out, [n][bt][128]) + per-node scores.
// grid (N_, 3), 256 thr: bt_local = tid&31 (wave-minor!), g = tid>>5.
// Wave carries 2 distinct W rows at a time -> 2-way LDS aliasing (free).
// Per-thread: x row in 64 regs; 16 Wp-dots + 16 Ws-dots + 2 score-dots.
// ---------------------------------------------------------------------------
__global__ __launch_bounds__(256) void k_proj(const void* __restrict__ xin,
                                              const float* __restrict__ Wp32,
                                              const float* __restrict__ Ws32,
                                              const float* __restrict__ aS,
                                              const float* __restrict__ aT,
                                              const int* __restrict__ flags,
                                              u16* __restrict__ projT,
                                              u16* __restrict__ skipT,
                                              float* __restrict__ sTs,
                                              float* __restrict__ sTt)
{
    __shared__ u16 Wl[2 * HF * FIN];   // Wp rows 0..127, Ws rows 128..255; 32 KB
    const int tid = threadIdx.x;
    const int n   = blockIdx.x;
    const int bt  = blockIdx.y * 32 + (tid & 31);
    const int g   = tid >> 5;
    const bool bf = flags[0] != 0;

    for (int i = tid; i < HF * FIN; i += 256) {
        Wl[i]            = f2bf(Wp32[i]);
        Wl[HF * FIN + i] = f2bf(Ws32[i]);
    }
    __syncthreads();

    // x row -> 64 fp32 regs
    float xr[FIN];
    const size_t xoff = ((size_t)bt * N_ + n) * FIN;
    if (bf) {
        const uint4* xp = (const uint4*)((const u16*)xin + xoff);
#pragma unroll
        for (int c = 0; c < 8; c++) {
            const uint4 q = xp[c];
            const int kb = c * 8;
            unpack2(q.x, xr[kb+0], xr[kb+1]);
            unpack2(q.y, xr[kb+2], xr[kb+3]);
            unpack2(q.z, xr[kb+4], xr[kb+5]);
            unpack2(q.w, xr[kb+6], xr[kb+7]);
        }
    } else {
        const float4* xp = (const float4*)((const float*)xin + xoff);
#pragma unroll
        for (int c = 0; c < 16; c++) {
            const float4 q = xp[c];
            const int kb = c * 4;
            xr[kb+0] = q.x; xr[kb+1] = q.y; xr[kb+2] = q.z; xr[kb+3] = q.w;
        }
    }

    // scores for head g (aS/aT small, L1-resident)
    {
        const float4* ar = (const float4*)(aS + g * FIN);
        const float4* br = (const float4*)(aT + g * FIN);
        float s1 = 0.f, s2 = 0.f;
#pragma unroll
        for (int c = 0; c < 16; c++) {
            const float4 a = ar[c], b = br[c];
            const int kb = c * 4;
            s1 = fmaf(a.x, xr[kb+0], s1); s1 = fmaf(a.y, xr[kb+1], s1);
            s1 = fmaf(a.z, xr[kb+2], s1); s1 = fmaf(a.w, xr[kb+3], s1);
            s2 = fmaf(b.x, xr[kb+0], s2); s2 = fmaf(b.y, xr[kb+1], s2);
            s2 = fmaf(b.z, xr[kb+2], s2); s2 = fmaf(b.w, xr[kb+3], s2);
        }
        const size_t so = ((size_t)n * BT + bt) * H_ + g;
        sTs[so] = s1;
        sTt[so] = s2;
    }

    // 16 proj + 16 skip outputs for heads-slice g
    for (int j = 0; j < 16; j++) {
        const int row = (g * 16 + j) * FIN;
        const uint4* wp = (const uint4*)(Wl + row);
        const uint4* ws = (const uint4*)(Wl + HF * FIN + row);
        float aP = 0.f, aK = 0.f;
#pragma unroll
        for (int c = 0; c < 8; c++) {
            const uint4 q = wp[c];
            const int kb = c * 8;
            float lo, hi;
            unpack2(q.x, lo, hi); aP = fmaf(lo, xr[kb+0], aP); aP = fmaf(hi, xr[kb+1], aP);
            unpack2(q.y, lo, hi); aP = fmaf(lo, xr[kb+2], aP); aP = fmaf(hi, xr[kb+3], aP);
            unpack2(q.z, lo, hi); aP = fmaf(lo, xr[kb+4], aP); aP = fmaf(hi, xr[kb+5], aP);
            unpack2(q.w, lo, hi); aP = fmaf(lo, xr[kb+6], aP); aP = fmaf(hi, xr[kb+7], aP);
        }
#pragma unroll
        for (int c = 0; c < 8; c++) {
            const uint4 q = ws[c];
            const int kb = c * 8;
            float lo, hi;
            unpack2(q.x, lo, hi); aK = fmaf(lo, xr[kb+0], aK); aK = fmaf(hi, xr[kb+1], aK);
            unpack2(q.y, lo, hi); aK = fmaf(lo, xr[kb+2], aK); aK = fmaf(hi, xr[kb+3], aK);
            unpack2(q.z, lo, hi); aK = fmaf(lo, xr[kb+4], aK); aK = fmaf(hi, xr[kb+5], aK);
            unpack2(q.w, lo, hi); aK = fmaf(lo, xr[kb+6], aK); aK = fmaf(hi, xr[kb+7], aK);
        }
        const size_t o = ((size_t)n * BT + bt) * HF + g * 16 + j;
        projT[o] = f2bf(aP);
        skipT[o] = f2bf(aK);
    }
}

// ---------------------------------------------------------------------------
// K3: coalesced max-reduce over node scores. grid (96, 2): by=0 -> sTs,
// by=1 -> sTt; each block covers 8000 consecutive floats.
// ---------------------------------------------------------------------------
__global__ __launch_bounds__(256) void k_gmax(const float* __restrict__ sTs,
                                              const float* __restrict__ sTt,
                                              float* __restrict__ partial)
{
    const int tid = threadIdx.x;
    const float* base = (blockIdx.y ? sTt : sTs) + (size_t)blockIdx.x * 8000;
    float m = -INFINITY;
    for (int i = tid; i < 8000; i += 256) m = fmaxf(m, base[i]);
#pragma unroll
    for (int d = 32; d >= 1; d >>= 1) m = fmaxf(m, __shfl_xor(m, d, 64));
    __shared__ float wm[4];
    if ((tid & 63) == 0) wm[tid >> 6] = m;
    __syncthreads();
    if (tid == 0)
        partial[blockIdx.y * 128 + blockIdx.x] =
            fmaxf(fmaxf(wm[0], wm[1]), fmaxf(wm[2], wm[3]));
}

// K3b: gmax = leaky(max(ss) + max(st))  — an upper bound on the true edge
// max; softmax is shift-invariant (eps effect <=1e-9 rel at score sigma~0.5).
__global__ __launch_bounds__(256) void k_fin(const float* __restrict__ partial,
                                             float* __restrict__ gmax)
{
    const int tid = threadIdx.x;
    float m1 = (tid < 96) ? partial[tid]       : -INFINITY;
    float m2 = (tid < 96) ? partial[128 + tid] : -INFINITY;
#pragma unroll
    for (int d = 32; d >= 1; d >>= 1) {
        m1 = fmaxf(m1, __shfl_xor(m1, d, 64));
        m2 = fmaxf(m2, __shfl_xor(m2, d, 64));
    }
    __shared__ float w1[4], w2[4];
    if ((tid & 63) == 0) { w1[tid >> 6] = m1; w2[tid >> 6] = m2; }
    __syncthreads();
    if (tid == 0) {
        const float M = fmaxf(fmaxf(w1[0], w1[1]), fmaxf(w1[2], w1[3])) +
                        fmaxf(fmaxf(w2[0], w2[1]), fmaxf(w2[2], w2[3]));
        *gmax = fmaxf(M, 0.2f * M);   // leaky of the bound
    }
}

// ---------------------------------------------------------------------------
// K4: attention gather in proj space. grid (N_, 24), 256 thr = 4 waves;
// wave -> bt = by*4 + wave_id; lane j2 owns outputs 2*j2, 2*j2+1 (h = j2>>3).
// Per edge: 256B coalesced proj-row load + 32B score gather + 1 exp + 2 fma.
// Edge loop batched x8 (uniform predicates) -> 16 outstanding loads/wave.
// Per-thread state ~3 accumulators: no spill (r4 lesson).
// ---------------------------------------------------------------------------
__global__ __launch_bounds__(256) void k_att(const u16* __restrict__ projT,
                                             const u16* __restrict__ skipT,
                                             const float* __restrict__ sTs,
                                             const float* __restrict__ sTt,
                                             const int* __restrict__ offs,
                                             const int* __restrict__ csrS,
                                             const float* __restrict__ gmaxp,
                                             const int* __restrict__ flags,
                                             void* __restrict__ out)
{
    const int n   = blockIdx.x;
    const int tid = threadIdx.x;
    const int bt  = blockIdx.y * 4 + (tid >> 6);
    const int j2  = tid & 63;
    const int h   = j2 >> 3;

    __shared__ int csrL[64];

    const float g  = *gmaxp;
    const float st = sTt[((size_t)n * BT + bt) * H_ + h];

    float y0 = 0.f, y1 = 0.f, den = 0.f;
    const int e0 = offs[n], e1 = offs[n + 1];

    for (int base = e0; base < e1; base += 64) {
        const int cnt = min(64, e1 - base);
        __syncthreads();
        if (tid < cnt) csrL[tid] = csrS[base + tid];
        __syncthreads();

        for (int i0 = 0; i0 < cnt; i0 += 8) {
            float wv[8];
            u32   pv[8];
#pragma unroll
            for (int k = 0; k < 8; k++) {
                const int i = i0 + k;
                const int idx = (i < cnt) ? i : 0;       // clamp: slot 0 valid
                const int s = csrL[idx];
                const float ss = sTs[((size_t)s * BT + bt) * H_ + h];
                float sc = ss + st;
                sc = fmaxf(sc, 0.2f * sc);               // leaky_relu(0.2)
                const float w = __expf(sc - g);
                wv[k] = (i < cnt) ? w : 0.f;
                pv[k] = *(const u32*)(projT + ((size_t)s * BT + bt) * HF + 2 * j2);
            }
#pragma unroll
            for (int k = 0; k < 8; k++) {
                float lo, hi;
                unpack2(pv[k], lo, hi);
                den += wv[k];
                y0 = fmaf(wv[k], lo, y0);
                y1 = fmaf(wv[k], hi, y1);
            }
        }
    }

    const float rden = 1.0f / (den + 1e-16f);
    float sk0, sk1;
    {
        const u32 sq = *(const u32*)(skipT + ((size_t)n * BT + bt) * HF + 2 * j2);
        unpack2(sq, sk0, sk1);
    }
    float o0 = fmaf(y0, rden, sk0);
    float o1 = fmaf(y1, rden, sk1);
    o0 = o0 > 0.f ? o0 : expm1f(o0);                     // ELU
    o1 = o1 > 0.f ? o1 : expm1f(o1);

    const size_t ob = ((size_t)bt * N_ + n) * HF + 2 * j2;
    if (flags[0]) {
        ((u32*)out)[ob >> 1] = (u32)f2bf(o0) | ((u32)f2bf(o1) << 16);
    } else {
        *(float2*)((float*)out + ob) = make_float2(o0, o1);
    }
}

// ---------------------------------------------------------------------------
extern "C" void kernel_launch(void* const* d_in, const int* in_sizes, int n_in,
                              void* d_out, int out_size, void* d_ws, size_t ws_size,
                              hipStream_t stream)
{
    const void* x   = d_in[0];
    const u32*  ew  = (const u32*)d_in[1];
    const void* Wp  = d_in[2];
    const void* as_ = d_in[3];
    const void* at_ = d_in[4];
    const void* Ws  = d_in[5];

    float* ws      = (float*)d_ws;
    int*   flags   = (int*)(ws + OFF_FLAGS);
    float* aS      = ws + OFF_AS;
    float* aT      = ws + OFF_AT;
    float* gmax    = ws + OFF_GMAX;
    float* partial = ws + OFF_PART;
    int*   offs    = (int*)(ws + OFF_OFFS);
    int*   csrS    = (int*)(ws + OFF_CSR);
    float* Wp32    = ws + OFF_WP32;
    float* Ws32    = ws + OFF_WS32;
    float* sTs     = ws + OFF_STS;
    float* sTt     = ws + OFF_STT;
    u16*   projT   = (u16*)(ws + OFF_PROJ);
    u16*   skipT   = (u16*)(ws + OFF_SKIP);

    k_prep<<<1, 256, 0, stream>>>((const u32*)x, ew, Wp, Ws, as_, at_,
                                  flags, Wp32, Ws32, aS, aT);
    k_csr <<<1, 1024, 0, stream>>>(ew, flags, offs, csrS);
    k_proj<<<dim3(N_, 3), 256, 0, stream>>>(x, Wp32, Ws32, aS, aT, flags,
                                            projT, skipT, sTs, sTt);
    k_gmax<<<dim3(96, 2), 256, 0, stream>>>(sTs, sTt, partial);
    k_fin <<<1, 256, 0, stream>>>(partial, gmax);
    k_att <<<dim3(N_, 24), 256, 0, stream>>>(projT, skipT, sTs, sTt,
                                             offs, csrS, gmax, flags, d_out);
}

// Round 6
// 199.422 us; speedup vs baseline: 23.5166x; 1.8056x over previous
//
#include <hip/hip_runtime.h>
#include <math.h>

#define B_   8
#define T_   12
#define BT   96      // B*T
#define N_   1000
#define FIN  64
#define H_   8
#define FOUT 16
#define HF   128     // H*FOUT
#define E_   8000
#define NW   272     // W' rows: 128 proj + 128 skip + 8 aS + 8 aT

typedef unsigned short u16;
typedef unsigned int   u32;
typedef __attribute__((ext_vector_type(8))) short  short8;   // 8 bf16 (4 VGPR)
typedef __attribute__((ext_vector_type(4))) float  float4v;  // MFMA acc

__device__ __forceinline__ float bf2f(u16 u) {
    return __uint_as_float(((u32)u) << 16);
}
__device__ __forceinline__ void unpack2(u32 q, float& lo, float& hi) {
    lo = __uint_as_float(q << 16);
    hi = __uint_as_float(q & 0xffff0000u);
}
__device__ __forceinline__ u16 f2bf(float f) {
    u32 x = __float_as_uint(f);
    u32 r = (x + 0x7fffu + ((x >> 16) & 1u)) >> 16;   // RNE
    return (u16)r;
}

// ---------------------------------------------------------------------------
// Workspace carve (float-element offsets). Total 13,841,972 floats ~ 55.4 MB
// (same size as round 5 — proven available).
// ---------------------------------------------------------------------------
#define OFF_FLAGS   0         // 4 ints
#define OFF_GMAX    4         // 4
#define OFF_PART    8         // 256
#define OFF_OFFS    264       // 1004 ints
#define OFF_CSR     1268      // 8000 ints
#define OFF_WALL    9268      // W' bf16 [272][64] = 17408 u16 = 8704 floats
#define OFF_STS     17972     // 768000  sT_src fp32 [n][bt][8]
#define OFF_STT     785972    // 768000  sT_trg fp32 [n][bt][8]
#define OFF_PROJ    1553972   // projT bf16 [n][bt][128] = 12.288M u16
#define OFF_SKIP    7697972   // skipT bf16 [n][bt][128]
// end: 13,841,972

// ---------------------------------------------------------------------------
// K0: dtype probes + build packed W' (bf16 [272][64]):
//   rows   0..127 : W_proj
//   rows 128..255 : W_skip
//   rows 256..263 : aS[h] = a_src[h] @ W_proj_h   (score fold)
//   rows 264..271 : aT[h] = a_trg[h] @ W_proj_h
// ---------------------------------------------------------------------------
__global__ __launch_bounds__(256) void k_prep(const u32* __restrict__ xw,
                                              const u32* __restrict__ ew,
                                              const void* __restrict__ Wp,
                                              const void* __restrict__ Ws,
                                              const void* __restrict__ as_,
                                              const void* __restrict__ at_,
                                              int* __restrict__ flags,
                                              u16* __restrict__ Wall)
{
    __shared__ float WpL[HF * FIN];   // 32 KB canonical fp32 W_proj
    __shared__ int votes;
    __shared__ u32 orAcc;
    __shared__ int flagL;
    const int tid = threadIdx.x;

    if (tid == 0) { votes = 0; orAcc = 0u; }
    __syncthreads();

    {   // bf16-vs-fp32 probe on x
        const u32 w = xw[tid];
        const int e = (int)((w >> 7) & 0xFFu);
        if (e == 0 || (e >= 95 && e <= 140)) atomicAdd(&votes, 1);
    }
    {   // int64-vs-int32 probe on edge_index
        u32 o = 0;
        for (int i = 2 * tid + 1; i < 16000; i += 512) o |= ew[i];
        atomicOr(&orAcc, o);
    }
    __syncthreads();
    if (tid == 0) {
        flagL = (votes >= 160) ? 1 : 0;
        flags[0] = flagL;
        flags[1] = (orAcc == 0u) ? 1 : 0;
    }
    __syncthreads();
    const bool bf = flagL != 0;

    for (int i = tid; i < HF * FIN; i += 256) {
        const float wp = bf ? bf2f(((const u16*)Wp)[i]) : ((const float*)Wp)[i];
        const float wv = bf ? bf2f(((const u16*)Ws)[i]) : ((const float*)Ws)[i];
        WpL[i] = wp;
        Wall[i]            = f2bf(wp);
        Wall[HF * FIN + i] = f2bf(wv);
    }
    __syncthreads();

    for (int q = tid; q < H_ * FIN; q += 256) {
        const int h = q >> 6, k = q & 63;
        float s1 = 0.f, s2 = 0.f;
#pragma unroll
        for (int f = 0; f < FOUT; f++) {
            const float w = WpL[(h * FOUT + f) * FIN + k];
            const float a1 = bf ? bf2f(((const u16*)as_)[h * FOUT + f])
                                : ((const float*)as_)[h * FOUT + f];
            const float a2 = bf ? bf2f(((const u16*)at_)[h * FOUT + f])
                                : ((const float*)at_)[h * FOUT + f];
            s1 = fmaf(a1, w, s1);
            s2 = fmaf(a2, w, s2);
        }
        Wall[256 * FIN + q] = f2bf(s1);   // aS rows
        Wall[264 * FIN + q] = f2bf(s2);   // aT rows
    }
}

// ---------------------------------------------------------------------------
// K1: decode edges + build CSR (edges grouped by target). 1 block, 1024 thr.
// ---------------------------------------------------------------------------
__global__ __launch_bounds__(1024) void k_csr(const u32* __restrict__ ew,
                                              const int* __restrict__ flags,
                                              int* __restrict__ offs,
                                              int* __restrict__ csrS)
{
    __shared__ int cnt[1024];
    __shared__ int scan[1024];
    __shared__ int cursor[1024];
    const int tid = threadIdx.x;
    const bool i64 = flags[1] != 0;

    cnt[tid] = 0;
    __syncthreads();
    for (int e = tid; e < E_; e += 1024) {
        const int t = i64 ? (int)ew[2 * (E_ + e)] : (int)ew[E_ + e];
        atomicAdd(&cnt[t], 1);
    }
    __syncthreads();

    scan[tid] = cnt[tid];
    __syncthreads();
    for (int d = 1; d < 1024; d <<= 1) {
        int t = (tid >= d) ? scan[tid - d] : 0;
        __syncthreads();
        scan[tid] += t;
        __syncthreads();
    }
    int excl = (tid == 0) ? 0 : scan[tid - 1];
    cursor[tid] = excl;
    if (tid < N_) offs[tid] = excl;
    if (tid == 0) offs[N_] = E_;
    __syncthreads();

    for (int e = tid; e < E_; e += 1024) {
        const int s = i64 ? (int)ew[2 * e] : (int)ew[e];
        const int t = i64 ? (int)ew[2 * (E_ + e)] : (int)ew[E_ + e];
        int pos = atomicAdd(&cursor[t], 1);
        csrS[pos] = s;
    }
}

// ---------------------------------------------------------------------------
// K2: MFMA GEMM  C[96000 x 272] = X[96000 x 64] . W'^T, fused epilogue
// scattering C into projT/skipT (bf16, [n][bt][.]) and sTs/sTt (fp32).
// 256 thr = 4 waves; wave = one 16-row M-tile (block = 64 rows, grid 1500).
// A-frag: A[m=lane&15][k=quad*8+j] -> one 16B load/frag straight from global.
// B-frag: W' row (t*16 + lane&15), k-chunk quad -> L1-resident.
// C/D:    col=lane&15, row=quad*4+reg (m89-verified mapping).
// No LDS, ~45 VGPR -> high occupancy; 2 MFMA per N-tile (K=64).
// ---------------------------------------------------------------------------
__global__ __launch_bounds__(256) void k_mfma(const void* __restrict__ xin,
                                              const u16* __restrict__ Wall,
                                              const int* __restrict__ flags,
                                              u16* __restrict__ projT,
                                              u16* __restrict__ skipT,
                                              float* __restrict__ sTs,
                                              float* __restrict__ sTt)
{
    const int tid  = threadIdx.x;
    const int wid  = tid >> 6;
    const int lid  = tid & 63;
    const int m    = lid & 15;
    const int q    = lid >> 4;
    const int base = blockIdx.x * 64 + wid * 16;

    // ---- A fragments (rows base+m, k = q*8..q*8+7 and +32) ----
    short8 a0, a1;
    {
        const size_t xoff = (size_t)(base + m) * FIN + q * 8;
        if (flags[0]) {
            const u16* xp = (const u16*)xin + xoff;
            a0 = *reinterpret_cast<const short8*>(xp);
            a1 = *reinterpret_cast<const short8*>(xp + 32);
        } else {
            const float* xp = (const float*)xin + xoff;
            union { short8 v; u16 e[8]; } p0, p1;
#pragma unroll
            for (int i = 0; i < 8; i++) {
                p0.e[i] = f2bf(xp[i]);
                p1.e[i] = f2bf(xp[i + 32]);
            }
            a0 = p0.v;
            a1 = p1.v;
        }
    }

    // ---- transposed output row bases for my 4 C rows ----
    u32 ob[4];
#pragma unroll
    for (int r = 0; r < 4; r++) {
        const u32 row = (u32)(base + q * 4 + r);   // row = bt*1000 + n
        const u32 bt  = row / 1000u;
        const u32 n   = row - bt * 1000u;
        ob[r] = n * BT + bt;
    }

    const short8* Wv = reinterpret_cast<const short8*>(Wall);  // row*8 + chunk

    // ---- 16 proj/skip N-tiles ----
#pragma unroll
    for (int t = 0; t < 16; t++) {
        const int wr = t * 16 + m;
        const short8 b0 = Wv[wr * 8 + q];
        const short8 b1 = Wv[wr * 8 + q + 4];
        float4v acc = {0.f, 0.f, 0.f, 0.f};
        acc = __builtin_amdgcn_mfma_f32_16x16x32_bf16(a0, b0, acc, 0, 0, 0);
        acc = __builtin_amdgcn_mfma_f32_16x16x32_bf16(a1, b1, acc, 0, 0, 0);

        u16* dst = (t < 8) ? projT : skipT;
        const int col = ((t < 8) ? t : (t - 8)) * 16 + m;
#pragma unroll
        for (int r = 0; r < 4; r++)
            dst[(size_t)ob[r] * HF + col] = f2bf(acc[r]);
    }

    // ---- score N-tile (cols 256..271 of W') ----
    {
        const int wr = 256 + m;
        const short8 b0 = Wv[wr * 8 + q];
        const short8 b1 = Wv[wr * 8 + q + 4];
        float4v acc = {0.f, 0.f, 0.f, 0.f};
        acc = __builtin_amdgcn_mfma_f32_16x16x32_bf16(a0, b0, acc, 0, 0, 0);
        acc = __builtin_amdgcn_mfma_f32_16x16x32_bf16(a1, b1, acc, 0, 0, 0);

        float* dstS = (m < 8) ? sTs : sTt;
        const int h = m & 7;
#pragma unroll
        for (int r = 0; r < 4; r++)
            dstS[(size_t)ob[r] * H_ + h] = acc[r];
    }
}

// ---------------------------------------------------------------------------
// K3: coalesced max-reduce over node scores. grid (96, 2).
// ---------------------------------------------------------------------------
__global__ __launch_bounds__(256) void k_gmax(const float* __restrict__ sTs,
                                              const float* __restrict__ sTt,
                                              float* __restrict__ partial)
{
    const int tid = threadIdx.x;
    const float* base = (blockIdx.y ? sTt : sTs) + (size_t)blockIdx.x * 8000;
    float m = -INFINITY;
    for (int i = tid; i < 8000; i += 256) m = fmaxf(m, base[i]);
#pragma unroll
    for (int d = 32; d >= 1; d >>= 1) m = fmaxf(m, __shfl_xor(m, d, 64));
    __shared__ float wm[4];
    if ((tid & 63) == 0) wm[tid >> 6] = m;
    __syncthreads();
    if (tid == 0)
        partial[blockIdx.y * 128 + blockIdx.x] =
            fmaxf(fmaxf(wm[0], wm[1]), fmaxf(wm[2], wm[3]));
}

// K3b: gmax = leaky(max(ss) + max(st)) — upper bound; softmax shift-invariant.
__global__ __launch_bounds__(256) void k_fin(const float* __restrict__ partial,
                                             float* __restrict__ gmax)
{
    const int tid = threadIdx.x;
    float m1 = (tid < 96) ? partial[tid]       : -INFINITY;
    float m2 = (tid < 96) ? partial[128 + tid] : -INFINITY;
#pragma unroll
    for (int d = 32; d >= 1; d >>= 1) {
        m1 = fmaxf(m1, __shfl_xor(m1, d, 64));
        m2 = fmaxf(m2, __shfl_xor(m2, d, 64));
    }
    __shared__ float w1[4], w2[4];
    if ((tid & 63) == 0) { w1[tid >> 6] = m1; w2[tid >> 6] = m2; }
    __syncthreads();
    if (tid == 0) {
        const float M = fmaxf(fmaxf(w1[0], w1[1]), fmaxf(w1[2], w1[3])) +
                        fmaxf(fmaxf(w2[0], w2[1]), fmaxf(w2[2], w2[3]));
        *gmax = fmaxf(M, 0.2f * M);
    }
}

// ---------------------------------------------------------------------------
// K4: attention gather in proj space (unchanged from round 5 — correct, no
// spill). grid (N_, 24), 256 thr = 4 waves; wave -> bt; lane owns 2 outputs.
// ---------------------------------------------------------------------------
__global__ __launch_bounds__(256) void k_att(const u16* __restrict__ projT,
                                             const u16* __restrict__ skipT,
                                             const float* __restrict__ sTs,
                                             const float* __restrict__ sTt,
                                             const int* __restrict__ offs,
                                             const int* __restrict__ csrS,
                                             const float* __restrict__ gmaxp,
                                             const int* __restrict__ flags,
                                             void* __restrict__ out)
{
    const int n   = blockIdx.x;
    const int tid = threadIdx.x;
    const int bt  = blockIdx.y * 4 + (tid >> 6);
    const int j2  = tid & 63;
    const int h   = j2 >> 3;

    __shared__ int csrL[64];

    const float g  = *gmaxp;
    const float st = sTt[((size_t)n * BT + bt) * H_ + h];

    float y0 = 0.f, y1 = 0.f, den = 0.f;
    const int e0 = offs[n], e1 = offs[n + 1];

    for (int base = e0; base < e1; base += 64) {
        const int cnt = min(64, e1 - base);
        __syncthreads();
        if (tid < cnt) csrL[tid] = csrS[base + tid];
        __syncthreads();

        for (int i0 = 0; i0 < cnt; i0 += 8) {
            float wv[8];
            u32   pv[8];
#pragma unroll
            for (int k = 0; k < 8; k++) {
                const int i = i0 + k;
                const int idx = (i < cnt) ? i : 0;
                const int s = csrL[idx];
                const float ss = sTs[((size_t)s * BT + bt) * H_ + h];
                float sc = ss + st;
                sc = fmaxf(sc, 0.2f * sc);               // leaky_relu(0.2)
                const float w = __expf(sc - g);
                wv[k] = (i < cnt) ? w : 0.f;
                pv[k] = *(const u32*)(projT + ((size_t)s * BT + bt) * HF + 2 * j2);
            }
#pragma unroll
            for (int k = 0; k < 8; k++) {
                float lo, hi;
                unpack2(pv[k], lo, hi);
                den += wv[k];
                y0 = fmaf(wv[k], lo, y0);
                y1 = fmaf(wv[k], hi, y1);
            }
        }
    }

    const float rden = 1.0f / (den + 1e-16f);
    float sk0, sk1;
    {
        const u32 sq = *(const u32*)(skipT + ((size_t)n * BT + bt) * HF + 2 * j2);
        unpack2(sq, sk0, sk1);
    }
    float o0 = fmaf(y0, rden, sk0);
    float o1 = fmaf(y1, rden, sk1);
    o0 = o0 > 0.f ? o0 : expm1f(o0);                     // ELU
    o1 = o1 > 0.f ? o1 : expm1f(o1);

    const size_t ob = ((size_t)bt * N_ + n) * HF + 2 * j2;
    if (flags[0]) {
        ((u32*)out)[ob >> 1] = (u32)f2bf(o0) | ((u32)f2bf(o1) << 16);
    } else {
        *(float2*)((float*)out + ob) = make_float2(o0, o1);
    }
}

// ---------------------------------------------------------------------------
extern "C" void kernel_launch(void* const* d_in, const int* in_sizes, int n_in,
                              void* d_out, int out_size, void* d_ws, size_t ws_size,
                              hipStream_t stream)
{
    const void* x   = d_in[0];
    const u32*  ew  = (const u32*)d_in[1];
    const void* Wp  = d_in[2];
    const void* as_ = d_in[3];
    const void* at_ = d_in[4];
    const void* Ws  = d_in[5];

    float* ws      = (float*)d_ws;
    int*   flags   = (int*)(ws + OFF_FLAGS);
    float* gmax    = ws + OFF_GMAX;
    float* partial = ws + OFF_PART;
    int*   offs    = (int*)(ws + OFF_OFFS);
    int*   csrS    = (int*)(ws + OFF_CSR);
    u16*   Wall    = (u16*)(ws + OFF_WALL);
    float* sTs     = ws + OFF_STS;
    float* sTt     = ws + OFF_STT;
    u16*   projT   = (u16*)(ws + OFF_PROJ);
    u16*   skipT   = (u16*)(ws + OFF_SKIP);

    k_prep<<<1, 256, 0, stream>>>((const u32*)x, ew, Wp, Ws, as_, at_, flags, Wall);
    k_csr <<<1, 1024, 0, stream>>>(ew, flags, offs, csrS);
    k_mfma<<<1500, 256, 0, stream>>>(x, Wall, flags, projT, skipT, sTs, sTt);
    k_gmax<<<dim3(96, 2), 256, 0, stream>>>(sTs, sTt, partial);
    k_fin <<<1, 256, 0, stream>>>(partial, gmax);
    k_att <<<dim3(1000, 24), 256, 0, stream>>>(projT, skipT, sTs, sTt,
                                               offs, csrS, gmax, flags, d_out);
}

// Round 7
// 169.665 us; speedup vs baseline: 27.6410x; 1.1754x over previous
//
#include <hip/hip_runtime.h>
#include <math.h>

#define B_   8
#define T_   12
#define BT   96      // B*T
#define N_   1000
#define FIN  64
#define H_   8
#define FOUT 16
#define HF   128     // H*FOUT
#define E_   8000
#define NW   272     // W' rows: 128 proj + 128 skip + 8 aS + 8 aT

typedef unsigned short u16;
typedef unsigned int   u32;
typedef __attribute__((ext_vector_type(8))) short  short8;   // 8 bf16 (4 VGPR)
typedef __attribute__((ext_vector_type(4))) float  float4v;  // MFMA acc

__device__ __forceinline__ float bf2f(u16 u) {
    return __uint_as_float(((u32)u) << 16);
}
__device__ __forceinline__ void unpack2(u32 q, float& lo, float& hi) {
    lo = __uint_as_float(q << 16);
    hi = __uint_as_float(q & 0xffff0000u);
}
__device__ __forceinline__ u16 f2bf(float f) {
    u32 x = __float_as_uint(f);
    u32 r = (x + 0x7fffu + ((x >> 16) & 1u)) >> 16;   // RNE
    return (u16)r;
}

// ---------------------------------------------------------------------------
// Workspace carve (float-element offsets) — same 55.4 MB footprint as r5/r6.
// ---------------------------------------------------------------------------
#define OFF_FLAGS   0         // 4 ints
#define OFF_OFFS    264       // 1004 ints
#define OFF_CSR     1268      // 8000 ints (stores src*BT, grouped by target)
#define OFF_WALL    9268      // W' bf16 [272][64] = 17408 u16 = 8704 floats
#define OFF_STS     17972     // 768000  sT_src fp32 [n][bt][8]
#define OFF_STT     785972    // 768000  sT_trg fp32 [n][bt][8]
#define OFF_PROJ    1553972   // projT bf16 [n][bt][128] = 12.288M u16
#define OFF_SKIP    7697972   // skipT bf16 [n][bt][128]

// ---------------------------------------------------------------------------
// K0 (fused prep+CSR, 1 block x 1024 thr):
//   dtype probes -> flags; packed W' bf16 [272][64] (proj | skip | aS | aT);
//   CSR grouped by target, storing src*BT (pre-scaled for k_att addressing).
// ---------------------------------------------------------------------------
__global__ __launch_bounds__(1024) void k_prep(const u32* __restrict__ xw,
                                               const u32* __restrict__ ew,
                                               const void* __restrict__ Wp,
                                               const void* __restrict__ Ws,
                                               const void* __restrict__ as_,
                                               const void* __restrict__ at_,
                                               int* __restrict__ flags,
                                               u16* __restrict__ Wall,
                                               int* __restrict__ offs,
                                               int* __restrict__ csrS)
{
    __shared__ float WpL[HF * FIN];   // 32 KB canonical fp32 W_proj
    __shared__ int cnt[1024];
    __shared__ int scan[1024];
    __shared__ int cursor[1024];
    __shared__ int votes;
    __shared__ u32 orAcc;
    __shared__ int fB, fE;
    const int tid = threadIdx.x;

    if (tid == 0) { votes = 0; orAcc = 0u; }
    __syncthreads();

    if (tid < 256) {   // bf16-vs-fp32 probe on x
        const u32 w = xw[tid];
        const int e = (int)((w >> 7) & 0xFFu);
        if (e == 0 || (e >= 95 && e <= 140)) atomicAdd(&votes, 1);
    }
    {   // int64-vs-int32 probe on edge_index
        u32 o = 0;
        for (int i = 2 * tid + 1; i < 16000; i += 2048) o |= ew[i];
        atomicOr(&orAcc, o);
    }
    __syncthreads();
    if (tid == 0) {
        fB = (votes >= 160) ? 1 : 0;
        fE = (orAcc == 0u) ? 1 : 0;
        flags[0] = fB;
        flags[1] = fE;
    }
    __syncthreads();
    const bool bf  = fB != 0;
    const bool i64 = fE != 0;

    // canonical W -> LDS + packed bf16 W'
    for (int i = tid; i < HF * FIN; i += 1024) {
        const float wp = bf ? bf2f(((const u16*)Wp)[i]) : ((const float*)Wp)[i];
        const float wv = bf ? bf2f(((const u16*)Ws)[i]) : ((const float*)Ws)[i];
        WpL[i] = wp;
        Wall[i]            = f2bf(wp);
        Wall[HF * FIN + i] = f2bf(wv);
    }
    cnt[tid] = 0;
    __syncthreads();

    // fold a through W_proj  +  CSR degree count (independent, same step)
    if (tid < H_ * FIN) {
        const int h = tid >> 6, k = tid & 63;
        float s1 = 0.f, s2 = 0.f;
#pragma unroll
        for (int f = 0; f < FOUT; f++) {
            const float w = WpL[(h * FOUT + f) * FIN + k];
            const float a1 = bf ? bf2f(((const u16*)as_)[h * FOUT + f])
                                : ((const float*)as_)[h * FOUT + f];
            const float a2 = bf ? bf2f(((const u16*)at_)[h * FOUT + f])
                                : ((const float*)at_)[h * FOUT + f];
            s1 = fmaf(a1, w, s1);
            s2 = fmaf(a2, w, s2);
        }
        Wall[256 * FIN + tid] = f2bf(s1);   // aS rows
        Wall[264 * FIN + tid] = f2bf(s2);   // aT rows
    }
    for (int e = tid; e < E_; e += 1024) {
        const int t = i64 ? (int)ew[2 * (E_ + e)] : (int)ew[E_ + e];
        atomicAdd(&cnt[t], 1);
    }
    __syncthreads();

    // exclusive scan over 1024 counts
    scan[tid] = cnt[tid];
    __syncthreads();
    for (int d = 1; d < 1024; d <<= 1) {
        int t = (tid >= d) ? scan[tid - d] : 0;
        __syncthreads();
        scan[tid] += t;
        __syncthreads();
    }
    int excl = (tid == 0) ? 0 : scan[tid - 1];
    cursor[tid] = excl;
    if (tid < N_) offs[tid] = excl;
    if (tid == 0) offs[N_] = E_;
    __syncthreads();

    for (int e = tid; e < E_; e += 1024) {
        const int s = i64 ? (int)ew[2 * e] : (int)ew[e];
        const int t = i64 ? (int)ew[2 * (E_ + e)] : (int)ew[E_ + e];
        int pos = atomicAdd(&cursor[t], 1);
        csrS[pos] = s * BT;                 // pre-scaled for k_att
    }
}

// ---------------------------------------------------------------------------
// K1: MFMA GEMM  C[96000 x 272] = X[96000 x 64] . W'^T  (unchanged from r6 —
// verified). Epilogue scatters into projT/skipT (bf16 [n][bt][.]) and
// sTs/sTt (fp32 [n][bt][8]).
// ---------------------------------------------------------------------------
__global__ __launch_bounds__(256) void k_mfma(const void* __restrict__ xin,
                                              const u16* __restrict__ Wall,
                                              const int* __restrict__ flags,
                                              u16* __restrict__ projT,
                                              u16* __restrict__ skipT,
                                              float* __restrict__ sTs,
                                              float* __restrict__ sTt)
{
    const int tid  = threadIdx.x;
    const int wid  = tid >> 6;
    const int lid  = tid & 63;
    const int m    = lid & 15;
    const int q    = lid >> 4;
    const int base = blockIdx.x * 64 + wid * 16;

    short8 a0, a1;
    {
        const size_t xoff = (size_t)(base + m) * FIN + q * 8;
        if (flags[0]) {
            const u16* xp = (const u16*)xin + xoff;
            a0 = *reinterpret_cast<const short8*>(xp);
            a1 = *reinterpret_cast<const short8*>(xp + 32);
        } else {
            const float* xp = (const float*)xin + xoff;
            union { short8 v; u16 e[8]; } p0, p1;
#pragma unroll
            for (int i = 0; i < 8; i++) {
                p0.e[i] = f2bf(xp[i]);
                p1.e[i] = f2bf(xp[i + 32]);
            }
            a0 = p0.v;
            a1 = p1.v;
        }
    }

    u32 ob[4];
#pragma unroll
    for (int r = 0; r < 4; r++) {
        const u32 row = (u32)(base + q * 4 + r);   // row = bt*1000 + n
        const u32 bt  = row / 1000u;
        const u32 n   = row - bt * 1000u;
        ob[r] = n * BT + bt;
    }

    const short8* Wv = reinterpret_cast<const short8*>(Wall);

#pragma unroll
    for (int t = 0; t < 16; t++) {
        const int wr = t * 16 + m;
        const short8 b0 = Wv[wr * 8 + q];
        const short8 b1 = Wv[wr * 8 + q + 4];
        float4v acc = {0.f, 0.f, 0.f, 0.f};
        acc = __builtin_amdgcn_mfma_f32_16x16x32_bf16(a0, b0, acc, 0, 0, 0);
        acc = __builtin_amdgcn_mfma_f32_16x16x32_bf16(a1, b1, acc, 0, 0, 0);

        u16* dst = (t < 8) ? projT : skipT;
        const int col = ((t < 8) ? t : (t - 8)) * 16 + m;
#pragma unroll
        for (int r = 0; r < 4; r++)
            dst[(size_t)ob[r] * HF + col] = f2bf(acc[r]);
    }

    {
        const int wr = 256 + m;
        const short8 b0 = Wv[wr * 8 + q];
        const short8 b1 = Wv[wr * 8 + q + 4];
        float4v acc = {0.f, 0.f, 0.f, 0.f};
        acc = __builtin_amdgcn_mfma_f32_16x16x32_bf16(a0, b0, acc, 0, 0, 0);
        acc = __builtin_amdgcn_mfma_f32_16x16x32_bf16(a1, b1, acc, 0, 0, 0);

        float* dstS = (m < 8) ? sTs : sTt;
        const int h = m & 7;
#pragma unroll
        for (int r = 0; r < 4; r++)
            dstS[(size_t)ob[r] * H_ + h] = acc[r];
    }
}

// ---------------------------------------------------------------------------
// K2: attention gather, lane-specialized weights. grid (N_, 24), 256 thr.
// Wave -> bt = by*4 + wid. Lane j2: OUTPUT role owns cols 2*j2,2*j2+1
// (h_out = j2>>3); WEIGHT role computes exp for edge-slot (j2>>3), head
// (j2&7) -> 8x less exp/score work; consumers fetch via __shfl.
// No global-max subtraction: softmax is shift-invariant and scores are
// structurally bounded (|s| <~ 15 << 88), so exp cannot overflow.
// ---------------------------------------------------------------------------
__global__ __launch_bounds__(256) void k_att(const u16* __restrict__ projT,
                                             const u16* __restrict__ skipT,
                                             const float* __restrict__ sTs,
                                             const float* __restrict__ sTt,
                                             const int* __restrict__ offs,
                                             const int* __restrict__ csrS,
                                             const int* __restrict__ flags,
                                             void* __restrict__ out)
{
    const int n   = blockIdx.x;
    const int tid = threadIdx.x;
    const int bt  = blockIdx.y * 4 + (tid >> 6);
    const int j2  = tid & 63;
    const int hw  = j2 & 7;     // weight-role head
    const int ho  = j2 >> 3;    // output-role head / weight-role edge slot

    __shared__ int csrL[64];    // holds src*BT

    const float st_w  = sTt[((size_t)n * BT + bt) * H_ + hw];
    const int   sboff = bt * H_ + hw;          // score addr = csrL*8 + sboff
    const u32   oboff = (u32)bt * HF + 2 * j2; // proj  addr = csrL*128 + oboff

    float y0 = 0.f, y1 = 0.f, den = 0.f;
    const int e0 = offs[n], e1 = offs[n + 1];

    for (int base = e0; base < e1; base += 64) {
        const int cnt = min(64, e1 - base);
        __syncthreads();
        if (tid < cnt) csrL[tid] = csrS[base + tid];
        __syncthreads();

        for (int i0 = 0; i0 < cnt; i0 += 8) {
            // weight role: one exp per lane
            const int eIdx = i0 + ho;
            const int sBTw = csrL[(eIdx < cnt) ? eIdx : 0];
            const float ss = sTs[(size_t)sBTw * H_ + sboff];
            float sc = ss + st_w;
            sc = fmaxf(sc, 0.2f * sc);                  // leaky_relu(0.2)
            const float wm = (eIdx < cnt) ? __expf(sc) : 0.f;

            // accumulate 8 edges; weight for (edge k, head ho) from lane k*8+ho
#pragma unroll
            for (int k = 0; k < 8; k++) {
                const float wk = __shfl(wm, k * 8 + ho, 64);
                const int sBT = csrL[(i0 + k < cnt) ? (i0 + k) : 0];
                const u32 pq = *(const u32*)(projT + (size_t)sBT * HF + oboff);
                float lo, hi;
                unpack2(pq, lo, hi);
                den += wk;
                y0 = fmaf(wk, lo, y0);
                y1 = fmaf(wk, hi, y1);
            }
        }
    }

    const float rden = __builtin_amdgcn_rcpf(den + 1e-16f);
    float sk0, sk1;
    {
        const u32 sq = *(const u32*)(skipT + ((size_t)n * BT + bt) * HF + 2 * j2);
        unpack2(sq, sk0, sk1);
    }
    float o0 = fmaf(y0, rden, sk0);
    float o1 = fmaf(y1, rden, sk1);
    o0 = o0 > 0.f ? o0 : __expf(o0) - 1.0f;             // ELU (bf16-exact enough)
    o1 = o1 > 0.f ? o1 : __expf(o1) - 1.0f;

    const size_t ob = ((size_t)bt * N_ + n) * HF + 2 * j2;
    if (flags[0]) {
        ((u32*)out)[ob >> 1] = (u32)f2bf(o0) | ((u32)f2bf(o1) << 16);
    } else {
        *(float2*)((float*)out + ob) = make_float2(o0, o1);
    }
}

// ---------------------------------------------------------------------------
extern "C" void kernel_launch(void* const* d_in, const int* in_sizes, int n_in,
                              void* d_out, int out_size, void* d_ws, size_t ws_size,
                              hipStream_t stream)
{
    const void* x   = d_in[0];
    const u32*  ew  = (const u32*)d_in[1];
    const void* Wp  = d_in[2];
    const void* as_ = d_in[3];
    const void* at_ = d_in[4];
    const void* Ws  = d_in[5];

    float* ws    = (float*)d_ws;
    int*   flags = (int*)(ws + OFF_FLAGS);
    int*   offs  = (int*)(ws + OFF_OFFS);
    int*   csrS  = (int*)(ws + OFF_CSR);
    u16*   Wall  = (u16*)(ws + OFF_WALL);
    float* sTs   = ws + OFF_STS;
    float* sTt   = ws + OFF_STT;
    u16*   projT = (u16*)(ws + OFF_PROJ);
    u16*   skipT = (u16*)(ws + OFF_SKIP);

    k_prep<<<1, 1024, 0, stream>>>((const u32*)x, ew, Wp, Ws, as_, at_,
                                   flags, Wall, offs, csrS);
    k_mfma<<<1500, 256, 0, stream>>>(x, Wall, flags, projT, skipT, sTs, sTt);
    k_att <<<dim3(1000, 24), 256, 0, stream>>>(projT, skipT, sTs, sTt,
                                               offs, csrS, flags, d_out);
}